// Round 3
// baseline (122.565 us; speedup 1.0000x reference)
//
#include <hip/hip_runtime.h>

#define N_  8
#define D_  64
#define H_  64
#define W_  64
#define HW_ (H_ * W_)
#define KK  25

// ---------------------------------------------------------------------------
// Kernel 1: per-block nonzero partial counts. 512 blocks x 256 threads; each
// block covers 4096 contiguous elements (64 blocks per batch n). Wave ballot
// popcount -> LDS combine -> exact partial written to pc/pq[blockIdx]. Every
// slot is written every call, so no memset and no atomics are needed.
// ---------------------------------------------------------------------------
__global__ __launch_bounds__(256) void count_nz_kernel(
    const float4* __restrict__ cur, const float4* __restrict__ prev,
    unsigned int* __restrict__ pc, unsigned int* __restrict__ pq)
{
    __shared__ unsigned int sc[4], sp[4];
    const int t    = threadIdx.x;
    const int wid  = t >> 6;
    const int lane = t & 63;

    unsigned int wc = 0, wp = 0;
#pragma unroll
    for (int j = 0; j < 4; ++j) {
        int idx = blockIdx.x * 1024 + j * 256 + t;
        float4 a = cur[idx];
        float4 b = prev[idx];
        wc += (unsigned)__popcll(__ballot(a.x != 0.f));
        wc += (unsigned)__popcll(__ballot(a.y != 0.f));
        wc += (unsigned)__popcll(__ballot(a.z != 0.f));
        wc += (unsigned)__popcll(__ballot(a.w != 0.f));
        wp += (unsigned)__popcll(__ballot(b.x != 0.f));
        wp += (unsigned)__popcll(__ballot(b.y != 0.f));
        wp += (unsigned)__popcll(__ballot(b.z != 0.f));
        wp += (unsigned)__popcll(__ballot(b.w != 0.f));
    }
    if (lane == 0) { sc[wid] = wc; sp[wid] = wp; }
    __syncthreads();

    if (t == 0) {
        pc[blockIdx.x] = sc[0] + sc[1] + sc[2] + sc[3];
        pq[blockIdx.x] = sp[0] + sp[1] + sp[2] + sp[3];
    }
}

// ---------------------------------------------------------------------------
// Kernel 2: fused FeatureAlign. Block = (n, y): 512 blocks, 256 threads =
// 64 x-lanes x 4 d-groups (16 channels each). Window indices q[k] are
// ABSOLUTE clamped positions -> d-invariant VGPR offsets; the channel base
// pointer advances uniformly (dg forced scalar via readfirstlane), so loads
// compile to saddr-form global_load_dword with zero per-iteration VALU
// address math. Partial dots reduced across d-groups through LDS.
// ---------------------------------------------------------------------------
__global__ __launch_bounds__(256) void feature_align_kernel(
    const float* __restrict__ cur, const float* __restrict__ prev,
    const float* __restrict__ pm, float* __restrict__ out,
    const unsigned int* __restrict__ pc, const unsigned int* __restrict__ pq)
{
    __shared__ float red[4][KK][64];    // 25.6 KB partial dots
    __shared__ float wght[KK][64];      //  6.4 KB normalized weights
    __shared__ int   zflag[64];

    const int nb = blockIdx.x;          // 0..511
    const int n  = nb >> 6;
    const int y  = nb & 63;
    const int x  = threadIdx.x & 63;
    const int dg = __builtin_amdgcn_readfirstlane(threadIdx.x >> 6); // scalar
    const int p  = y * W_ + x;

    // Absolute clamped window indices (d-invariant) + validity.
    int  q[KK];
    bool valid[KK];
#pragma unroll
    for (int ky = 0; ky < 5; ++ky) {
#pragma unroll
        for (int kx = 0; kx < 5; ++kx) {
            int py = y + ky - 2;
            int px = x + kx - 2;
            valid[ky * 5 + kx] = (py >= 0) && (py < H_) && (px >= 0) && (px < W_);
            int cy = min(max(py, 0), H_ - 1);
            int cx = min(max(px, 0), W_ - 1);
            q[ky * 5 + kx] = cy * W_ + cx;
        }
    }

    const size_t nbase = (size_t)n * D_ * HW_;
    const float* cd = cur  + nbase + (size_t)dg * 16 * HW_;  // uniform base
    const float* pd = prev + nbase + (size_t)dg * 16 * HW_;  // uniform base

    float acc[KK];
#pragma unroll
    for (int k = 0; k < KK; ++k) acc[k] = 0.f;

    // 16 channels per d-group: 25 window dot partials. Per iteration:
    // 1 scalar pointer advance + 26 saddr-form loads + 25 FMA.
    for (int dd = 0; dd < 16; ++dd) {
        float c = cd[p];
#pragma unroll
        for (int k = 0; k < KK; ++k)
            acc[k] = fmaf(c, pd[q[k]], acc[k]);
        cd += HW_;
        pd += HW_;
    }

#pragma unroll
    for (int k = 0; k < KK; ++k) red[dg][k][x] = acc[k];
    __syncthreads();

    if (dg == 0) {
        // Reduce this batch's 64 count partials across the wave (lane = slot).
        unsigned int cc = pc[(n << 6) + x];
        unsigned int vv = pq[(n << 6) + x];
#pragma unroll
        for (int s = 32; s >= 1; s >>= 1) {
            cc += __shfl_xor(cc, s);
            vv += __shfl_xor(vv, s);
        }
        float scale = 1.0f / (((float)cc + 1e-8f) * ((float)vv + 1e-8f));

        float mass = 0.f;
        float cf[KK];
#pragma unroll
        for (int k = 0; k < KK; ++k) {
            float s = red[0][k][x] + red[1][k][x] + red[2][k][x] + red[3][k][x];
            float c = valid[k] ? fmaxf(s * scale, 0.f) : 0.f;
            cf[k] = c;
            mass += c;
        }
        bool zero = fabsf(mass) < 1e-7f;
        float inv = zero ? 0.f : 1.0f / mass;
#pragma unroll
        for (int k = 0; k < KK; ++k) wght[k][x] = cf[k] * inv;
        zflag[x] = zero ? 1 : 0;
    }
    __syncthreads();

    const float* pmd  = pm  + nbase + (size_t)dg * 16 * HW_;
    float*       outd = out + nbase + (size_t)dg * 16 * HW_;

    if (zflag[x]) {
        // Hot path on this data: straight copy of prev_mem (coalesced).
        for (int dd = 0; dd < 16; ++dd) {
            outd[p] = pmd[p];
            pmd += HW_;
            outd += HW_;
        }
    } else {
        float w[KK];
#pragma unroll
        for (int k = 0; k < KK; ++k) w[k] = wght[k][x];  // invalid k -> 0
        for (int dd = 0; dd < 16; ++dd) {
            float v = 0.f;
#pragma unroll
            for (int k = 0; k < KK; ++k)
                v = fmaf(w[k], pmd[q[k]], v);
            outd[p] = v;
            pmd += HW_;
            outd += HW_;
        }
    }
}

extern "C" void kernel_launch(void* const* d_in, const int* in_sizes, int n_in,
                              void* d_out, int out_size, void* d_ws, size_t ws_size,
                              hipStream_t stream)
{
    const float* cur  = (const float*)d_in[0];
    const float* prev = (const float*)d_in[1];
    const float* pm   = (const float*)d_in[2];
    float*       out  = (float*)d_out;
    unsigned int* pc  = (unsigned int*)d_ws;        // 512 partials (cur)
    unsigned int* pq  = pc + 512;                   // 512 partials (prev)

    count_nz_kernel<<<512, 256, 0, stream>>>(
        (const float4*)cur, (const float4*)prev, pc, pq);

    feature_align_kernel<<<512, 256, 0, stream>>>(cur, prev, pm, out, pc, pq);
}

// Round 4
// 89.056 us; speedup vs baseline: 1.3763x; 1.3763x over previous
//
#include <hip/hip_runtime.h>

#define N_  8
#define D_  64
#define H_  64
#define W_  64
#define HW_ (H_ * W_)
#define KK  25
#define DG  8     // d-groups per block
#define CPT 8     // channels per d-group thread

// ---------------------------------------------------------------------------
// Kernel 1: per-block nonzero partial counts. 512 blocks x 256 threads, each
// block covers 4096 contiguous elements (64 blocks per batch). Ballot popcount
// -> exact partial per block; no memset, no atomics.
// ---------------------------------------------------------------------------
__global__ __launch_bounds__(256) void count_nz_kernel(
    const float4* __restrict__ cur, const float4* __restrict__ prev,
    unsigned int* __restrict__ pc, unsigned int* __restrict__ pq)
{
    __shared__ unsigned int sc[4], sp[4];
    const int t    = threadIdx.x;
    const int wid  = t >> 6;
    const int lane = t & 63;

    unsigned int wc = 0, wp = 0;
#pragma unroll
    for (int j = 0; j < 4; ++j) {
        int idx = blockIdx.x * 1024 + j * 256 + t;
        float4 a = cur[idx];
        float4 b = prev[idx];
        wc += (unsigned)__popcll(__ballot(a.x != 0.f));
        wc += (unsigned)__popcll(__ballot(a.y != 0.f));
        wc += (unsigned)__popcll(__ballot(a.z != 0.f));
        wc += (unsigned)__popcll(__ballot(a.w != 0.f));
        wp += (unsigned)__popcll(__ballot(b.x != 0.f));
        wp += (unsigned)__popcll(__ballot(b.y != 0.f));
        wp += (unsigned)__popcll(__ballot(b.z != 0.f));
        wp += (unsigned)__popcll(__ballot(b.w != 0.f));
    }
    if (lane == 0) { sc[wid] = wc; sp[wid] = wp; }
    __syncthreads();
    if (t == 0) {
        pc[blockIdx.x] = sc[0] + sc[1] + sc[2] + sc[3];
        pq[blockIdx.x] = sp[0] + sp[1] + sp[2] + sp[3];
    }
}

// ---------------------------------------------------------------------------
// Kernel 2: fused FeatureAlign.
// Grid: 1024 blocks = (n, y, x-half). Block: 256 threads = 32 x-lanes x 8
// d-groups (8 channels each) -> 4 blocks/CU, 16 waves/CU.
// Addressing: window row bases are WAVE-UNIFORM (cy depends only on y) ->
// scalar pointers; only qx[5] (clamped x offsets) are per-lane -> saddr-form
// loads, ~no VALU address math, low VGPR. Channel loop fully unrolled with
// depth-1 register prefetch so vmcnt waits are partial, not full drains.
// ---------------------------------------------------------------------------
__global__ __launch_bounds__(256, 4) void feature_align_kernel(
    const float* __restrict__ cur, const float* __restrict__ prev,
    const float* __restrict__ pm, float* __restrict__ out,
    const unsigned int* __restrict__ pc, const unsigned int* __restrict__ pq)
{
    __shared__ float red[DG][KK][32];   // 25.6 KB partial dots
    __shared__ float wght[KK][32];      //  3.2 KB normalized weights
    __shared__ int   zflag[32];

    const int b  = blockIdx.x;          // 0..1023
    const int n  = b >> 7;
    const int y  = (b >> 1) & 63;
    const int xh = b & 1;
    const int xl = threadIdx.x & 31;    // lane-in-row
    const int dg = threadIdx.x >> 5;    // 0..7
    const int x  = xh * 32 + xl;

    // Per-lane clamped x offsets (valid lanes are unclamped-exact).
    unsigned qx[5];
#pragma unroll
    for (int kx = 0; kx < 5; ++kx)
        qx[kx] = (unsigned)min(max(x + kx - 2, 0), W_ - 1);
    // Block-uniform clamped rows (scalar).
    int qy[5];
#pragma unroll
    for (int ky = 0; ky < 5; ++ky)
        qy[ky] = min(max(y + ky - 2, 0), H_ - 1);

    const size_t nbase = (size_t)n * D_ * HW_;
    const int    d0    = dg * CPT;
    const unsigned xu  = (unsigned)x;

    float acc[KK];
#pragma unroll
    for (int k = 0; k < KK; ++k) acc[k] = 0.f;

    // ---- prefetch channel d0 ----
    float c0, buf[KK];
    {
        const float* ch = prev + nbase + (size_t)d0 * HW_;
        c0 = (cur + nbase + (size_t)d0 * HW_ + (size_t)y * W_)[xu];
#pragma unroll
        for (int ky = 0; ky < 5; ++ky) {
            const float* row = ch + (size_t)qy[ky] * W_;   // scalar base
#pragma unroll
            for (int kx = 0; kx < 5; ++kx)
                buf[ky * 5 + kx] = row[qx[kx]];            // saddr load
        }
    }
    // ---- pipelined channel loop ----
#pragma unroll
    for (int dd = 0; dd < CPT - 1; ++dd) {
        const float* chn = prev + nbase + (size_t)(d0 + dd + 1) * HW_;
        float c1 = (cur + nbase + (size_t)(d0 + dd + 1) * HW_ + (size_t)y * W_)[xu];
        float nbuf[KK];
#pragma unroll
        for (int ky = 0; ky < 5; ++ky) {
            const float* row = chn + (size_t)qy[ky] * W_;
#pragma unroll
            for (int kx = 0; kx < 5; ++kx)
                nbuf[ky * 5 + kx] = row[qx[kx]];
        }
#pragma unroll
        for (int k = 0; k < KK; ++k) acc[k] = fmaf(c0, buf[k], acc[k]);
        c0 = c1;
#pragma unroll
        for (int k = 0; k < KK; ++k) buf[k] = nbuf[k];
    }
#pragma unroll
    for (int k = 0; k < KK; ++k) acc[k] = fmaf(c0, buf[k], acc[k]);

#pragma unroll
    for (int k = 0; k < KK; ++k) red[dg][k][xl] = acc[k];
    __syncthreads();

    // ---- weights (first 32 lanes of wave 0) ----
    if (threadIdx.x < 32) {
        unsigned int cc = pc[(n << 6) + xl] + pc[(n << 6) + 32 + xl];
        unsigned int vv = pq[(n << 6) + xl] + pq[(n << 6) + 32 + xl];
#pragma unroll
        for (int s = 16; s >= 1; s >>= 1) {
            cc += __shfl_xor(cc, s);
            vv += __shfl_xor(vv, s);
        }
        float scale = 1.0f / (((float)cc + 1e-8f) * ((float)vv + 1e-8f));

        float mass = 0.f;
        float cf[KK];
#pragma unroll
        for (int k = 0; k < KK; ++k) {
            float s = 0.f;
#pragma unroll
            for (int g = 0; g < DG; ++g) s += red[g][k][xl];
            int ky = k / 5, kx = k % 5;
            int py = y + ky - 2, px = x + kx - 2;
            bool valid = (py >= 0) && (py < H_) && (px >= 0) && (px < W_);
            float c = valid ? fmaxf(s * scale, 0.f) : 0.f;
            cf[k] = c;
            mass += c;
        }
        bool zero = fabsf(mass) < 1e-7f;
        float inv = zero ? 0.f : 1.0f / mass;
#pragma unroll
        for (int k = 0; k < KK; ++k) wght[k][xl] = cf[k] * inv;
        zflag[xl] = zero ? 1 : 0;
    }
    __syncthreads();

    // ---- output: copy (zero mass, hot path) or weighted gather ----
    if (zflag[xl]) {
#pragma unroll
        for (int dd = 0; dd < CPT; ++dd) {
            const float* pr = pm  + nbase + (size_t)(d0 + dd) * HW_ + (size_t)y * W_;
            float*       orow = out + nbase + (size_t)(d0 + dd) * HW_ + (size_t)y * W_;
            orow[xu] = pr[xu];
        }
    } else {
        float w[KK];
#pragma unroll
        for (int k = 0; k < KK; ++k) w[k] = wght[k][xl];   // invalid k -> 0
#pragma unroll
        for (int dd = 0; dd < CPT; ++dd) {
            const float* ch = pm + nbase + (size_t)(d0 + dd) * HW_;
            float v = 0.f;
#pragma unroll
            for (int ky = 0; ky < 5; ++ky) {
                const float* row = ch + (size_t)qy[ky] * W_;
#pragma unroll
                for (int kx = 0; kx < 5; ++kx)
                    v = fmaf(w[ky * 5 + kx], row[qx[kx]], v);
            }
            (out + nbase + (size_t)(d0 + dd) * HW_ + (size_t)y * W_)[xu] = v;
        }
    }
}

extern "C" void kernel_launch(void* const* d_in, const int* in_sizes, int n_in,
                              void* d_out, int out_size, void* d_ws, size_t ws_size,
                              hipStream_t stream)
{
    const float* cur  = (const float*)d_in[0];
    const float* prev = (const float*)d_in[1];
    const float* pm   = (const float*)d_in[2];
    float*       out  = (float*)d_out;
    unsigned int* pc  = (unsigned int*)d_ws;        // 512 partials (cur)
    unsigned int* pq  = pc + 512;                   // 512 partials (prev)

    count_nz_kernel<<<512, 256, 0, stream>>>(
        (const float4*)cur, (const float4*)prev, pc, pq);

    feature_align_kernel<<<1024, 256, 0, stream>>>(cur, prev, pm, out, pc, pq);
}

// Round 5
// 88.053 us; speedup vs baseline: 1.3919x; 1.0114x over previous
//
#include <hip/hip_runtime.h>

#define N_  8
#define D_  64
#define H_  64
#define W_  64
#define HW_ (H_ * W_)
#define KK  25

// ---------------------------------------------------------------------------
// Kernel 1: per-block nonzero partial counts (unchanged, ~3 us).
// 512 blocks x 256 threads, 4096 elems/block, 64 blocks per batch.
// ---------------------------------------------------------------------------
__global__ __launch_bounds__(256) void count_nz_kernel(
    const float4* __restrict__ cur, const float4* __restrict__ prev,
    unsigned int* __restrict__ pc, unsigned int* __restrict__ pq)
{
    __shared__ unsigned int sc[4], sp[4];
    const int t    = threadIdx.x;
    const int wid  = t >> 6;
    const int lane = t & 63;

    unsigned int wc = 0, wp = 0;
#pragma unroll
    for (int j = 0; j < 4; ++j) {
        int idx = blockIdx.x * 1024 + j * 256 + t;
        float4 a = cur[idx];
        float4 b = prev[idx];
        wc += (unsigned)__popcll(__ballot(a.x != 0.f));
        wc += (unsigned)__popcll(__ballot(a.y != 0.f));
        wc += (unsigned)__popcll(__ballot(a.z != 0.f));
        wc += (unsigned)__popcll(__ballot(a.w != 0.f));
        wp += (unsigned)__popcll(__ballot(b.x != 0.f));
        wp += (unsigned)__popcll(__ballot(b.y != 0.f));
        wp += (unsigned)__popcll(__ballot(b.z != 0.f));
        wp += (unsigned)__popcll(__ballot(b.w != 0.f));
    }
    if (lane == 0) { sc[wid] = wc; sp[wid] = wp; }
    __syncthreads();
    if (t == 0) {
        pc[blockIdx.x] = sc[0] + sc[1] + sc[2] + sc[3];
        pq[blockIdx.x] = sp[0] + sp[1] + sp[2] + sp[3];
    }
}

// ---------------------------------------------------------------------------
// Kernel 2: fused FeatureAlign, float2-vectorized.
// Grid: 256 blocks = (n, y-pair). Block: 512 threads = 8 waves; wave w = d-
// group w (8 channels, wave-uniform -> saddr loads); lane = (row r, xq):
// 2 rows x 32 xq, each thread covers 2 px (x0=2*xq) of its row.
// Per channel: 1 cur float2 + 15 window float2 (contiguous across lanes)
// + 50 FMA. Cross-dg reduction in LDS red[4][25][128] (dg>=4 adds in place).
// Weights/zflag aliased into red[0]/red[1] after a barrier.
// ---------------------------------------------------------------------------
__global__ __launch_bounds__(512, 2) void feature_align_kernel(
    const float* __restrict__ cur, const float* __restrict__ prev,
    const float* __restrict__ pm, float* __restrict__ out,
    const unsigned int* __restrict__ pc, const unsigned int* __restrict__ pq)
{
    __shared__ float red[4][KK][128];   // 51.2 KB; later aliased: red[0]=wght, red[1][0]=zflag

    const int b    = blockIdx.x;                 // 0..255
    const int n    = b >> 5;                     // batch
    const int y0   = (b & 31) * 2;               // row pair
    const int lane = threadIdx.x & 63;
    const int dg   = __builtin_amdgcn_readfirstlane(threadIdx.x >> 6); // 0..7, wave-uniform
    const int r    = lane >> 5;                  // row within pair
    const int xq   = lane & 31;
    const int x0   = xq * 2;
    const int y    = y0 + r;
    const int pix0 = r * 64 + x0;                // pixel index in block [0,128)

    // d-invariant per-lane byte offsets (32-bit, saddr-friendly).
    int cb[3];
#pragma unroll
    for (int i = 0; i < 3; ++i)
        cb[i] = min(max(x0 - 2 + 2 * i, 0), W_ - 2);     // even -> 8B aligned
    unsigned voff[5][3];
#pragma unroll
    for (int ky = 0; ky < 5; ++ky) {
        int qy = min(max(y + ky - 2, 0), H_ - 1);
#pragma unroll
        for (int i = 0; i < 3; ++i)
            voff[ky][i] = (unsigned)((qy * W_ + cb[i]) * 4);
    }
    const unsigned curoff = (unsigned)((y * W_ + x0) * 4);

    const size_t nbase = (size_t)n * D_ * HW_;
    const char* curb  = (const char*)(cur  + nbase + (size_t)dg * 8 * HW_);
    const char* prevb = (const char*)(prev + nbase + (size_t)dg * 8 * HW_);

    float acc0[KK], acc1[KK];
#pragma unroll
    for (int k = 0; k < KK; ++k) { acc0[k] = 0.f; acc1[k] = 0.f; }

    // ---- dot-product phase: 8 channels, contiguous float2 loads ----
#pragma unroll
    for (int dd = 0; dd < 8; ++dd) {
        const char* cch = curb  + (size_t)dd * HW_ * 4;
        const char* pch = prevb + (size_t)dd * HW_ * 4;
        float2 c = *(const float2*)(cch + curoff);
        float2 t[5][3];
#pragma unroll
        for (int ky = 0; ky < 5; ++ky)
#pragma unroll
            for (int i = 0; i < 3; ++i)
                t[ky][i] = *(const float2*)(pch + voff[ky][i]);
#pragma unroll
        for (int ky = 0; ky < 5; ++ky) {
            float v[6] = { t[ky][0].x, t[ky][0].y, t[ky][1].x,
                           t[ky][1].y, t[ky][2].x, t[ky][2].y };
#pragma unroll
            for (int kx = 0; kx < 5; ++kx) {
                acc0[ky * 5 + kx] = fmaf(c.x, v[kx],     acc0[ky * 5 + kx]);
                acc1[ky * 5 + kx] = fmaf(c.y, v[kx + 1], acc1[ky * 5 + kx]);
            }
        }
    }

    // ---- cross-dg reduction: dg 0-3 write, dg 4-7 add in place ----
    if (dg < 4) {
#pragma unroll
        for (int k = 0; k < KK; ++k)
            *(float2*)&red[dg][k][pix0] = make_float2(acc0[k], acc1[k]);
    }
    __syncthreads();
    if (dg >= 4) {
#pragma unroll
        for (int k = 0; k < KK; ++k) {
            float2 t2 = *(float2*)&red[dg - 4][k][pix0];
            t2.x += acc0[k]; t2.y += acc1[k];
            *(float2*)&red[dg - 4][k][pix0] = t2;
        }
    }
    __syncthreads();

    // ---- weights: 128 lanes, one pixel each ----
    const bool active = threadIdx.x < 128;
    float cf[KK];
    float inv = 0.f;
    bool  zero = true;
    if (active) {
        const int pix = threadIdx.x;
        const int rr  = pix >> 6;
        const int xx  = pix & 63;

        unsigned int ccnt = pc[(n << 6) + (threadIdx.x & 63)];
        unsigned int vcnt = pq[(n << 6) + (threadIdx.x & 63)];
#pragma unroll
        for (int s = 32; s >= 1; s >>= 1) {
            ccnt += __shfl_xor(ccnt, s);
            vcnt += __shfl_xor(vcnt, s);
        }
        float scale = 1.0f / (((float)ccnt + 1e-8f) * ((float)vcnt + 1e-8f));

        float mass = 0.f;
#pragma unroll
        for (int k = 0; k < KK; ++k) {
            float s = red[0][k][pix] + red[1][k][pix]
                    + red[2][k][pix] + red[3][k][pix];
            int ky = k / 5, kx = k % 5;
            int py = y0 + rr + ky - 2;
            int pxc = xx + kx - 2;
            bool val = (py >= 0) && (py < H_) && (pxc >= 0) && (pxc < W_);
            float c = val ? fmaxf(s * scale, 0.f) : 0.f;
            cf[k] = c;
            mass += c;
        }
        zero = fabsf(mass) < 1e-7f;
        inv  = zero ? 0.f : 1.0f / mass;
    }
    __syncthreads();
    if (active) {
        const int pix = threadIdx.x;
#pragma unroll
        for (int k = 0; k < KK; ++k) red[0][k][pix] = cf[k] * inv;  // wght
        red[1][0][pix] = zero ? 1.f : 0.f;                          // zflag
    }
    __syncthreads();

    // ---- output phase ----
    const char* pmb  = (const char*)(pm  + nbase + (size_t)dg * 8 * HW_);
    char*       outb = (char*)(out + nbase + (size_t)dg * 8 * HW_);

    const float zf0 = red[1][0][pix0];
    const float zf1 = red[1][0][pix0 + 1];

    if (zf0 != 0.f && zf1 != 0.f) {
        // Hot path on this data: straight float2 copy of prev_mem.
#pragma unroll
        for (int dd = 0; dd < 8; ++dd) {
            float2 m = *(const float2*)(pmb + (size_t)dd * HW_ * 4 + curoff);
            *(float2*)(outb + (size_t)dd * HW_ * 4 + curoff) = m;
        }
    } else {
        float w0[KK], w1[KK];
#pragma unroll
        for (int k = 0; k < KK; ++k) {
            float2 ww = *(float2*)&red[0][k][pix0];
            w0[k] = ww.x; w1[k] = ww.y;
        }
#pragma unroll
        for (int dd = 0; dd < 8; ++dd) {
            const char* pch = pmb + (size_t)dd * HW_ * 4;
            float2 t2[5][3];
#pragma unroll
            for (int ky = 0; ky < 5; ++ky)
#pragma unroll
                for (int i = 0; i < 3; ++i)
                    t2[ky][i] = *(const float2*)(pch + voff[ky][i]);
            float v0 = 0.f, v1 = 0.f;
#pragma unroll
            for (int ky = 0; ky < 5; ++ky) {
                float v[6] = { t2[ky][0].x, t2[ky][0].y, t2[ky][1].x,
                               t2[ky][1].y, t2[ky][2].x, t2[ky][2].y };
#pragma unroll
                for (int kx = 0; kx < 5; ++kx) {
                    v0 = fmaf(w0[ky * 5 + kx], v[kx],     v0);
                    v1 = fmaf(w1[ky * 5 + kx], v[kx + 1], v1);
                }
            }
            float2 m = *(const float2*)(pch + curoff);
            float2 o;
            o.x = (zf0 != 0.f) ? m.x : v0;
            o.y = (zf1 != 0.f) ? m.y : v1;
            *(float2*)(outb + (size_t)dd * HW_ * 4 + curoff) = o;
        }
    }
}

extern "C" void kernel_launch(void* const* d_in, const int* in_sizes, int n_in,
                              void* d_out, int out_size, void* d_ws, size_t ws_size,
                              hipStream_t stream)
{
    const float* cur  = (const float*)d_in[0];
    const float* prev = (const float*)d_in[1];
    const float* pm   = (const float*)d_in[2];
    float*       out  = (float*)d_out;
    unsigned int* pc  = (unsigned int*)d_ws;        // 512 partials (cur)
    unsigned int* pq  = pc + 512;                   // 512 partials (prev)

    count_nz_kernel<<<512, 256, 0, stream>>>(
        (const float4*)cur, (const float4*)prev, pc, pq);

    feature_align_kernel<<<256, 512, 0, stream>>>(cur, prev, pm, out, pc, pq);
}

// Round 6
// 86.486 us; speedup vs baseline: 1.4172x; 1.0181x over previous
//
#include <hip/hip_runtime.h>

#define N_  8
#define D_  64
#define H_  64
#define W_  64
#define HW_ (H_ * W_)
#define KK  25

// ---------------------------------------------------------------------------
// Kernel 1: per-block nonzero partial counts of cur and prev; ALSO streams
// prev_mem (counted into pr, never consumed) purely to warm L3 for kernel 2's
// pm loads. 512 blocks x 256 threads, 4096 elems/block, 64 blocks per batch.
// Exact partials, no memset, no atomics.
// ---------------------------------------------------------------------------
__global__ __launch_bounds__(256) void count_nz_kernel(
    const float4* __restrict__ cur, const float4* __restrict__ prev,
    const float4* __restrict__ pmv,
    unsigned int* __restrict__ pc, unsigned int* __restrict__ pq,
    unsigned int* __restrict__ pr)
{
    __shared__ unsigned int sc[4], sp[4], sr[4];
    const int t    = threadIdx.x;
    const int wid  = t >> 6;
    const int lane = t & 63;

    unsigned int wc = 0, wp = 0, wr = 0;
#pragma unroll
    for (int j = 0; j < 4; ++j) {
        int idx = blockIdx.x * 1024 + j * 256 + t;
        float4 a = cur[idx];
        float4 b = prev[idx];
        float4 m = pmv[idx];
        wc += (unsigned)__popcll(__ballot(a.x != 0.f));
        wc += (unsigned)__popcll(__ballot(a.y != 0.f));
        wc += (unsigned)__popcll(__ballot(a.z != 0.f));
        wc += (unsigned)__popcll(__ballot(a.w != 0.f));
        wp += (unsigned)__popcll(__ballot(b.x != 0.f));
        wp += (unsigned)__popcll(__ballot(b.y != 0.f));
        wp += (unsigned)__popcll(__ballot(b.z != 0.f));
        wp += (unsigned)__popcll(__ballot(b.w != 0.f));
        wr += (unsigned)__popcll(__ballot(m.x != 0.f));
        wr += (unsigned)__popcll(__ballot(m.y != 0.f));
        wr += (unsigned)__popcll(__ballot(m.z != 0.f));
        wr += (unsigned)__popcll(__ballot(m.w != 0.f));
    }
    if (lane == 0) { sc[wid] = wc; sp[wid] = wp; sr[wid] = wr; }
    __syncthreads();
    if (t == 0) {
        pc[blockIdx.x] = sc[0] + sc[1] + sc[2] + sc[3];
        pq[blockIdx.x] = sp[0] + sp[1] + sp[2] + sp[3];
        pr[blockIdx.x] = sr[0] + sr[1] + sr[2] + sr[3];
    }
}

// ---------------------------------------------------------------------------
// Kernel 2: fused FeatureAlign, float2-vectorized, latency-overlapped.
// Grid: 256 blocks = (n, y-pair). Block: 512 threads = 8 waves = 8 d-groups
// (wave-uniform -> saddr loads); lane = (row r, xq): 2 rows x 32 float2-cols.
// New vs R5: pm center float2s + count partials prefetched BEFORE the dot
// loads (output hot path = pure stores after the weights barrier; counts off
// the critical path); redundant center reloads and the extra barrier removed.
// ---------------------------------------------------------------------------
__global__ __launch_bounds__(512, 1) void feature_align_kernel(
    const float* __restrict__ cur, const float* __restrict__ prev,
    const float* __restrict__ pm, float* __restrict__ out,
    const unsigned int* __restrict__ pc, const unsigned int* __restrict__ pq)
{
    __shared__ float red[4][KK][128];   // 51.2 KB; aliased later: red[0]=wght, red[1][0]=zflag

    const int b    = blockIdx.x;                 // 0..255
    const int n    = b >> 5;                     // batch
    const int y0   = (b & 31) * 2;               // row pair
    const int lane = threadIdx.x & 63;
    const int dg   = __builtin_amdgcn_readfirstlane(threadIdx.x >> 6); // 0..7
    const int r    = lane >> 5;                  // row within pair
    const int xq   = lane & 31;
    const int x0   = xq * 2;
    const int y    = y0 + r;
    const int pix0 = r * 64 + x0;                // pixel index in block [0,128)

    // d-invariant per-lane byte offsets.
    int cb[3];
#pragma unroll
    for (int i = 0; i < 3; ++i)
        cb[i] = min(max(x0 - 2 + 2 * i, 0), W_ - 2);     // even -> 8B aligned
    unsigned voff[5][3];
#pragma unroll
    for (int ky = 0; ky < 5; ++ky) {
        int qy = min(max(y + ky - 2, 0), H_ - 1);
#pragma unroll
        for (int i = 0; i < 3; ++i)
            voff[ky][i] = (unsigned)((qy * W_ + cb[i]) * 4);
    }
    const unsigned curoff = (unsigned)((y * W_ + x0) * 4);

    const size_t nbase = (size_t)n * D_ * HW_;
    const char* curb  = (const char*)(cur  + nbase + (size_t)dg * 8 * HW_);
    const char* prevb = (const char*)(prev + nbase + (size_t)dg * 8 * HW_);
    const char* pmb   = (const char*)(pm   + nbase + (size_t)dg * 8 * HW_);
    char*       outb  = (char*)(out + nbase + (size_t)dg * 8 * HW_);

    // ---- EARLY prefetch: pm center values + count partials (off critical path)
    float2 pmc[8];
#pragma unroll
    for (int dd = 0; dd < 8; ++dd)
        pmc[dd] = *(const float2*)(pmb + (size_t)dd * HW_ * 4 + curoff);
    unsigned int ccnt = pc[(n << 6) + lane];
    unsigned int vcnt = pq[(n << 6) + lane];

    float acc0[KK], acc1[KK];
#pragma unroll
    for (int k = 0; k < KK; ++k) { acc0[k] = 0.f; acc1[k] = 0.f; }

    // ---- dot-product phase: 8 channels, contiguous float2 loads ----
#pragma unroll
    for (int dd = 0; dd < 8; ++dd) {
        const char* cch = curb  + (size_t)dd * HW_ * 4;
        const char* pch = prevb + (size_t)dd * HW_ * 4;
        float2 c = *(const float2*)(cch + curoff);
        float2 t[5][3];
#pragma unroll
        for (int ky = 0; ky < 5; ++ky)
#pragma unroll
            for (int i = 0; i < 3; ++i)
                t[ky][i] = *(const float2*)(pch + voff[ky][i]);
#pragma unroll
        for (int ky = 0; ky < 5; ++ky) {
            float v[6] = { t[ky][0].x, t[ky][0].y, t[ky][1].x,
                           t[ky][1].y, t[ky][2].x, t[ky][2].y };
#pragma unroll
            for (int kx = 0; kx < 5; ++kx) {
                acc0[ky * 5 + kx] = fmaf(c.x, v[kx],     acc0[ky * 5 + kx]);
                acc1[ky * 5 + kx] = fmaf(c.y, v[kx + 1], acc1[ky * 5 + kx]);
            }
        }
    }

    // ---- cross-dg reduction: dg 0-3 write, dg 4-7 add in place ----
    if (dg < 4) {
#pragma unroll
        for (int k = 0; k < KK; ++k)
            *(float2*)&red[dg][k][pix0] = make_float2(acc0[k], acc1[k]);
    }
    __syncthreads();
    if (dg >= 4) {
#pragma unroll
        for (int k = 0; k < KK; ++k) {
            float2 t2 = *(float2*)&red[dg - 4][k][pix0];
            t2.x += acc0[k]; t2.y += acc1[k];
            *(float2*)&red[dg - 4][k][pix0] = t2;
        }
    }
    __syncthreads();

    // ---- weights: first 128 threads, one pixel each ----
    if (threadIdx.x < 128) {
        const int pix = threadIdx.x;
        const int rr  = pix >> 6;
        const int xx  = pix & 63;

        // counts already in registers; wave-reduce now
        unsigned int cc = ccnt, vv = vcnt;
#pragma unroll
        for (int s = 32; s >= 1; s >>= 1) {
            cc += __shfl_xor(cc, s);
            vv += __shfl_xor(vv, s);
        }
        float scale = 1.0f / (((float)cc + 1e-8f) * ((float)vv + 1e-8f));

        float mass = 0.f;
        float cf[KK];
#pragma unroll
        for (int k = 0; k < KK; ++k) {
            float s = red[0][k][pix] + red[1][k][pix]
                    + red[2][k][pix] + red[3][k][pix];
            int ky = k / 5, kx = k % 5;
            int py  = y0 + rr + ky - 2;
            int pxc = xx + kx - 2;
            bool val = (py >= 0) && (py < H_) && (pxc >= 0) && (pxc < W_);
            float c = val ? fmaxf(s * scale, 0.f) : 0.f;
            cf[k] = c;
            mass += c;
        }
        bool  zero = fabsf(mass) < 1e-7f;
        float inv  = zero ? 0.f : 1.0f / mass;
        // Alias-safe: this thread read its red[0..3][*][pix] above; only this
        // thread writes column pix. No barrier needed between read and write.
#pragma unroll
        for (int k = 0; k < KK; ++k) red[0][k][pix] = cf[k] * inv;  // wght
        red[1][0][pix] = zero ? 1.f : 0.f;                          // zflag
    }
    __syncthreads();

    // ---- output phase ----
    const float zf0 = red[1][0][pix0];
    const float zf1 = red[1][0][pix0 + 1];

    if (zf0 != 0.f && zf1 != 0.f) {
        // Hot path: pure stores of the prefetched pm centers.
#pragma unroll
        for (int dd = 0; dd < 8; ++dd)
            *(float2*)(outb + (size_t)dd * HW_ * 4 + curoff) = pmc[dd];
    } else {
        float w0[KK], w1[KK];
#pragma unroll
        for (int k = 0; k < KK; ++k) {
            float2 ww = *(float2*)&red[0][k][pix0];
            w0[k] = ww.x; w1[k] = ww.y;
        }
#pragma unroll
        for (int dd = 0; dd < 8; ++dd) {
            const char* pch = pmb + (size_t)dd * HW_ * 4;
            float2 t2[5][3];
#pragma unroll
            for (int ky = 0; ky < 5; ++ky)
#pragma unroll
                for (int i = 0; i < 3; ++i)
                    t2[ky][i] = *(const float2*)(pch + voff[ky][i]);
            float v0 = 0.f, v1 = 0.f;
#pragma unroll
            for (int ky = 0; ky < 5; ++ky) {
                float v[6] = { t2[ky][0].x, t2[ky][0].y, t2[ky][1].x,
                               t2[ky][1].y, t2[ky][2].x, t2[ky][2].y };
#pragma unroll
                for (int kx = 0; kx < 5; ++kx) {
                    v0 = fmaf(w0[ky * 5 + kx], v[kx],     v0);
                    v1 = fmaf(w1[ky * 5 + kx], v[kx + 1], v1);
                }
            }
            float2 o;
            o.x = (zf0 != 0.f) ? pmc[dd].x : v0;
            o.y = (zf1 != 0.f) ? pmc[dd].y : v1;
            *(float2*)(outb + (size_t)dd * HW_ * 4 + curoff) = o;
        }
    }
}

extern "C" void kernel_launch(void* const* d_in, const int* in_sizes, int n_in,
                              void* d_out, int out_size, void* d_ws, size_t ws_size,
                              hipStream_t stream)
{
    const float* cur  = (const float*)d_in[0];
    const float* prev = (const float*)d_in[1];
    const float* pm   = (const float*)d_in[2];
    float*       out  = (float*)d_out;
    unsigned int* pc  = (unsigned int*)d_ws;        // 512 partials (cur)
    unsigned int* pq  = pc + 512;                   // 512 partials (prev)
    unsigned int* pr  = pq + 512;                   // 512 partials (pm, unused)

    count_nz_kernel<<<512, 256, 0, stream>>>(
        (const float4*)cur, (const float4*)prev, (const float4*)pm, pc, pq, pr);

    feature_align_kernel<<<256, 512, 0, stream>>>(cur, prev, pm, out, pc, pq);
}